// Round 1
// baseline (327.319 us; speedup 1.0000x reference)
//
#include <hip/hip_runtime.h>
#include <hip/hip_bf16.h>
#include <stdint.h>

// Problem constants (from reference)
#define NB 8
#define NT 2048
#define ND 512
#define NH 4
#define NDK 128
#define QKV_LD 1536   // row stride of qkv buffer (3*D)
#define KW 11

typedef unsigned short u16;
typedef __attribute__((ext_vector_type(4))) float f32x4;
typedef __attribute__((ext_vector_type(8))) short s16x8;   // 8 bf16 = 4 VGPR (guide §3)
typedef __attribute__((ext_vector_type(4))) unsigned short u16x4;

#define AS1 __attribute__((address_space(1)))
#define AS3 __attribute__((address_space(3)))

__device__ __forceinline__ u16 f2bf(float f){
  unsigned u = __float_as_uint(f);
  u += 0x7fffu + ((u >> 16) & 1u);      // RNE
  return (u16)(u >> 16);
}
__device__ __forceinline__ float bf2f(u16 h){ return __uint_as_float(((unsigned)h) << 16); }

// ---------------------------------------------------------------- convert x -> bf16
__global__ void cvt_f32_bf16(const float* __restrict__ in, u16* __restrict__ out, int n4){
  int i = blockIdx.x * blockDim.x + threadIdx.x;
  const int stride = gridDim.x * blockDim.x;
  for (; i < n4; i += stride){
    float4 v = reinterpret_cast<const float4*>(in)[i];
    u16x4 o = { f2bf(v.x), f2bf(v.y), f2bf(v.z), f2bf(v.w) };
    reinterpret_cast<u16x4*>(out)[i] = o;
  }
}

// ------------------------------------------- transpose + convert f32 (RxC) -> bf16 (CxR)
__global__ void transpose_cvt(const float* __restrict__ in, u16* __restrict__ out, int R, int C){
  __shared__ float tile[32][33];
  const int cb = blockIdx.x * 32, rb = blockIdx.y * 32;
  const int tx = threadIdx.x, ty = threadIdx.y;   // (32,8)
  #pragma unroll
  for (int i = 0; i < 4; ++i)
    tile[ty + i*8][tx] = in[(size_t)(rb + ty + i*8) * C + cb + tx];
  __syncthreads();
  #pragma unroll
  for (int i = 0; i < 4; ++i)
    out[(size_t)(cb + ty + i*8) * R + rb + tx] = f2bf(tile[tx][ty + i*8]);
}

// ------------------------------------------- per-(b,h) transpose of V: (t,dk) -> (dk,t), bf16
__global__ void vT_kernel(const u16* __restrict__ qkvb, u16* __restrict__ vT){
  __shared__ u16 tile[32][33];
  const int z = blockIdx.z, b = z >> 2, h = z & 3;
  const u16* in = qkvb + (size_t)b * NT * QKV_LD + 2*ND + h * NDK;  // v block of qkv
  u16* outp = vT + (size_t)z * NDK * NT;
  const int db = blockIdx.x * 32, tb = blockIdx.y * 32;
  const int tx = threadIdx.x, ty = threadIdx.y;   // (32,8)
  #pragma unroll
  for (int i = 0; i < 4; ++i)
    tile[ty + i*8][tx] = in[(size_t)(tb + ty + i*8) * QKV_LD + db + tx];
  __syncthreads();
  #pragma unroll
  for (int i = 0; i < 4; ++i)
    outp[(size_t)(db + ty + i*8) * NT + tb + tx] = tile[tx][ty + i*8];
}

// ---------------------------------------------------------------- bf16 GEMM  C = A * Bt^T + bias
// A: MxK row-major bf16.  Bt: NxK row-major bf16 (i.e. B transposed).
// EPI==0: C -> bf16 buffer.  EPI==1: C -> f32 out, += resid (fsmn memory already in out buffer).
// 128x128 tile, BK=32, 4 waves, 4x4 16x16x32 MFMA per wave. 2-phase (m97 structure).
template<int EPI>
__global__ __launch_bounds__(256, 2) void gemm_bt(
    const u16* __restrict__ A, const u16* __restrict__ Bt, const float* __restrict__ bias,
    u16* __restrict__ Cb, float* __restrict__ Cf, const float* __restrict__ resid,
    int M, int N, int Kd)
{
  __shared__ u16 As[128 * 32];
  __shared__ u16 Bs[128 * 32];
  const int tid = threadIdx.x;
  const int m0 = blockIdx.y * 128, n0 = blockIdx.x * 128;
  const int w = tid >> 6, l = tid & 63, wr = w >> 1, wc = w & 1;
  const int r15 = l & 15, g = l >> 4;

  f32x4 acc[4][4] = {};

  const int row = tid >> 2, kc = tid & 3;       // chunk -> (row, 16B-chunk-in-row)
  const u16* Ag0 = A  + (size_t)(m0 + row)      * Kd + kc * 8;
  const u16* Ag1 = A  + (size_t)(m0 + row + 64) * Kd + kc * 8;
  const u16* Bg0 = Bt + (size_t)(n0 + row)      * Kd + kc * 8;
  const u16* Bg1 = Bt + (size_t)(n0 + row + 64) * Kd + kc * 8;
  u16* Al0 = &As[(size_t)tid * 8];
  u16* Al1 = &As[2048 + (size_t)tid * 8];
  u16* Bl0 = &Bs[(size_t)tid * 8];
  u16* Bl1 = &Bs[2048 + (size_t)tid * 8];

  for (int k0 = 0; k0 < Kd; k0 += 32){
    __builtin_amdgcn_global_load_lds((AS1 void*)(Ag0 + k0), (AS3 void*)Al0, 16, 0, 0);
    __builtin_amdgcn_global_load_lds((AS1 void*)(Ag1 + k0), (AS3 void*)Al1, 16, 0, 0);
    __builtin_amdgcn_global_load_lds((AS1 void*)(Bg0 + k0), (AS3 void*)Bl0, 16, 0, 0);
    __builtin_amdgcn_global_load_lds((AS1 void*)(Bg1 + k0), (AS3 void*)Bl1, 16, 0, 0);
    __syncthreads();
    s16x8 af[4], bfr[4];
    #pragma unroll
    for (int m = 0; m < 4; ++m)
      af[m] = *reinterpret_cast<const s16x8*>(&As[(wr*64 + m*16 + r15) * 32 + g*8]);
    #pragma unroll
    for (int n = 0; n < 4; ++n)
      bfr[n] = *reinterpret_cast<const s16x8*>(&Bs[(wc*64 + n*16 + r15) * 32 + g*8]);
    #pragma unroll
    for (int m = 0; m < 4; ++m){
      #pragma unroll
      for (int n = 0; n < 4; ++n)
        acc[m][n] = __builtin_amdgcn_mfma_f32_16x16x32_bf16(af[m], bfr[n], acc[m][n], 0, 0, 0);
    }
    __syncthreads();
  }

  // epilogue: C/D layout col = lane&15, row = (lane>>4)*4 + j  (guide §3, m89-verified)
  #pragma unroll
  for (int m = 0; m < 4; ++m){
    const int gr0 = m0 + wr*64 + m*16 + g*4;
    #pragma unroll
    for (int n = 0; n < 4; ++n){
      const int gc = n0 + wc*64 + n*16 + r15;
      const float bv = bias[gc];
      #pragma unroll
      for (int j = 0; j < 4; ++j){
        const size_t idx = (size_t)(gr0 + j) * N + gc;
        const float v = acc[m][n][j] + bv;
        if (EPI == 0) Cb[idx] = f2bf(v);
        else          Cf[idx] = v + resid[idx];
      }
    }
  }
}

// ---------------------------------------------------------------- FSMN depthwise conv (K=11, centered)
// out[b][t][d] = m[t] * ( vm[t][d] + sum_i w[d][i]*vm[t+i-5][d] ),  vm = m*v
__device__ __forceinline__ void load_vm(const u16* vb, const float* mb, int tau, float& a, float& c){
  if ((unsigned)tau >= (unsigned)NT){ a = 0.f; c = 0.f; return; }
  const float m = mb[tau];
  const unsigned pv = *reinterpret_cast<const unsigned*>(vb + (size_t)tau * QKV_LD);
  a = m * bf2f((u16)(pv & 0xffffu));
  c = m * bf2f((u16)(pv >> 16));
}

__global__ void fsmn_kernel(const u16* __restrict__ qkvb, const float* __restrict__ mask,
                            const float* __restrict__ fsmn_w, float* __restrict__ out)
{
  const int b = blockIdx.y;
  const int t0 = blockIdx.x * 128;
  const int d0 = threadIdx.x * 2;
  float w0[KW], w1[KW];
  #pragma unroll
  for (int i = 0; i < KW; ++i){ w0[i] = fsmn_w[d0*KW + i]; w1[i] = fsmn_w[(d0+1)*KW + i]; }
  const u16* vb = qkvb + (size_t)b * NT * QKV_LD + 2*ND + d0;
  const float* mb = mask + (size_t)b * NT;
  float v0[KW], v1[KW];                       // sliding vm window, tau = t-5+i
  #pragma unroll
  for (int i = 0; i < KW; ++i) load_vm(vb, mb, t0 - 5 + i, v0[i], v1[i]);
  for (int t = t0; t < t0 + 128; ++t){
    const float m = mb[t];
    float c0 = 0.f, c1 = 0.f;
    #pragma unroll
    for (int i = 0; i < KW; ++i){ c0 += w0[i]*v0[i]; c1 += w1[i]*v1[i]; }
    float2 o; o.x = m * (c0 + v0[5]); o.y = m * (c1 + v1[5]);
    *reinterpret_cast<float2*>(out + (size_t)(b*NT + t) * ND + d0) = o;
    #pragma unroll
    for (int i = 0; i < KW - 1; ++i){ v0[i] = v0[i+1]; v1[i] = v1[i+1]; }
    load_vm(vb, mb, t + 6, v0[KW-1], v1[KW-1]);
  }
}

// ---------------------------------------------------------------- flash attention
// Block: 4 waves, 64 q-rows (16/wave). KV tiles of 64 keys. bf16 MFMA 16x16x32.
// K/V^T tiles staged via global_load_lds with XOR-swizzle (byte ^= (row&7)<<4) applied by
// pre-swizzling the per-lane GLOBAL source (rule #21: linear LDS dest + inverse-swz source).
__global__ __launch_bounds__(256, 2) void attn_kernel(
    const u16* __restrict__ qkvb, const u16* __restrict__ vT,
    const float* __restrict__ mask, u16* __restrict__ ctxb)
{
  __shared__ u16 Ks[64 * 128];     // [key][dk], swizzled
  __shared__ u16 Vs[128 * 64];     // [dk][key], swizzled
  __shared__ u16 Ps[4][16 * 64];   // per-wave P tile [qrow][key], swizzled
  const int tid = threadIdx.x;
  const int w = tid >> 6, l = tid & 63, g = l >> 4, r15 = l & 15;
  const int q0 = blockIdx.x * 64;
  const int bh = blockIdx.y, b = bh >> 2, h = bh & 3;
  const u16* qb  = qkvb + (size_t)b * NT * QKV_LD + h * NDK;
  const u16* kb  = qb + ND;
  const u16* vtb = vT + (size_t)bh * NDK * NT;
  const float* mkp = mask + (size_t)b * NT;
  const float scale = 0.08838834764831845f;   // 1/sqrt(128)

  // Q fragments in registers: A-frag lane holds row=l&15, k=(l>>4)*8..+8
  s16x8 qf[4];
  {
    const u16* qrow = qb + (size_t)(q0 + w*16 + r15) * QKV_LD;
    #pragma unroll
    for (int ks = 0; ks < 4; ++ks)
      qf[ks] = *reinterpret_cast<const s16x8*>(qrow + ks*32 + g*8);
  }
  float mrun[4], lrun[4];
  f32x4 oacc[8] = {};
  #pragma unroll
  for (int j = 0; j < 4; ++j){ mrun[j] = -1e30f; lrun[j] = 0.f; }

  for (int kv0 = 0; kv0 < NT; kv0 += 64){
    #pragma unroll
    for (int i = 0; i < 4; ++i){          // K: 64 keys x 128 dk
      const int c = tid + i*256;
      const int kr = c >> 4, kc = c & 15;
      const u16* gp = kb + (size_t)(kv0 + kr) * QKV_LD + ((kc ^ (kr & 7)) << 3);
      __builtin_amdgcn_global_load_lds((AS1 void*)gp, (AS3 void*)&Ks[c*8], 16, 0, 0);
    }
    #pragma unroll
    for (int i = 0; i < 4; ++i){          // V^T: 128 dk x 64 keys
      const int c = tid + i*256;
      const int dr = c >> 3, kc = c & 7;
      const u16* gp = vtb + (size_t)dr * NT + kv0 + ((kc ^ (dr & 7)) << 3);
      __builtin_amdgcn_global_load_lds((AS1 void*)gp, (AS3 void*)&Vs[c*8], 16, 0, 0);
    }
    __syncthreads();

    // S = Q K^T  (16 q-rows x 64 keys per wave)
    f32x4 sc[4] = {};
    #pragma unroll
    for (int n = 0; n < 4; ++n){
      const int krow = n*16 + r15;
      #pragma unroll
      for (int ks = 0; ks < 4; ++ks){
        const int cb = (ks*64 + g*16) ^ ((krow & 7) << 4);
        s16x8 kf = *reinterpret_cast<const s16x8*>(&Ks[krow*128 + (cb >> 1)]);
        sc[n] = __builtin_amdgcn_mfma_f32_16x16x32_bf16(qf[ks], kf, sc[n], 0, 0, 0);
      }
    }
    // mask + scale (masked key -> -1e30; online-softmax self-heals all-masked prefixes)
    float mkv[4];
    #pragma unroll
    for (int n = 0; n < 4; ++n) mkv[n] = mkp[kv0 + n*16 + r15];
    #pragma unroll
    for (int n = 0; n < 4; ++n){
      #pragma unroll
      for (int j = 0; j < 4; ++j)
        sc[n][j] = (mkv[n] == 0.f) ? -1e30f : sc[n][j] * scale;
    }
    // per-row (j within lane-group) online softmax
    float tmx[4];
    #pragma unroll
    for (int j = 0; j < 4; ++j)
      tmx[j] = fmaxf(fmaxf(sc[0][j], sc[1][j]), fmaxf(sc[2][j], sc[3][j]));
    #pragma unroll
    for (int d = 1; d < 16; d <<= 1){
      #pragma unroll
      for (int j = 0; j < 4; ++j) tmx[j] = fmaxf(tmx[j], __shfl_xor(tmx[j], d));
    }
    float corr[4];
    #pragma unroll
    for (int j = 0; j < 4; ++j){
      const float mn = fmaxf(mrun[j], tmx[j]);
      corr[j] = __expf(mrun[j] - mn);
      mrun[j] = mn;
    }
    float pvv[4][4];
    float ts[4] = {0.f, 0.f, 0.f, 0.f};
    #pragma unroll
    for (int n = 0; n < 4; ++n){
      #pragma unroll
      for (int j = 0; j < 4; ++j){
        const float p = __expf(sc[n][j] - mrun[j]);
        pvv[n][j] = p; ts[j] += p;
      }
    }
    #pragma unroll
    for (int d = 1; d < 16; d <<= 1){
      #pragma unroll
      for (int j = 0; j < 4; ++j) ts[j] += __shfl_xor(ts[j], d);
    }
    #pragma unroll
    for (int j = 0; j < 4; ++j) lrun[j] = lrun[j]*corr[j] + ts[j];
    #pragma unroll
    for (int n8 = 0; n8 < 8; ++n8){
      #pragma unroll
      for (int j = 0; j < 4; ++j) oacc[n8][j] *= corr[j];
    }
    // P -> per-wave LDS (bf16), swizzled; same-wave DS ops are in-order, no barrier needed
    #pragma unroll
    for (int n = 0; n < 4; ++n){
      #pragma unroll
      for (int j = 0; j < 4; ++j){
        const int prow = g*4 + j;
        const int cb = ((n*16 + r15) << 1) ^ ((prow & 7) << 4);
        Ps[w][prow*64 + (cb >> 1)] = f2bf(pvv[n][j]);
      }
    }
    // O += P V
    #pragma unroll
    for (int ks = 0; ks < 2; ++ks){
      const int cbp = (ks*64 + g*16) ^ ((r15 & 7) << 4);
      s16x8 pf = *reinterpret_cast<const s16x8*>(&Ps[w][r15*64 + (cbp >> 1)]);
      #pragma unroll
      for (int n8 = 0; n8 < 8; ++n8){
        const int vrow = n8*16 + r15;
        const int cb = (ks*64 + g*16) ^ ((vrow & 7) << 4);
        s16x8 vf = *reinterpret_cast<const s16x8*>(&Vs[vrow*64 + (cb >> 1)]);
        oacc[n8] = __builtin_amdgcn_mfma_f32_16x16x32_bf16(pf, vf, oacc[n8], 0, 0, 0);
      }
    }
    __syncthreads();
  }
  // epilogue: ctx -> bf16
  float rl[4];
  #pragma unroll
  for (int j = 0; j < 4; ++j) rl[j] = (lrun[j] > 0.f) ? 1.f / lrun[j] : 0.f;
  #pragma unroll
  for (int n8 = 0; n8 < 8; ++n8){
    #pragma unroll
    for (int j = 0; j < 4; ++j){
      const size_t r = (size_t)b*NT + q0 + w*16 + g*4 + j;
      ctxb[r*ND + h*NDK + n8*16 + r15] = f2bf(oacc[n8][j] * rl[j]);
    }
  }
}

// ---------------------------------------------------------------- launcher
extern "C" void kernel_launch(void* const* d_in, const int* in_sizes, int n_in,
                              void* d_out, int out_size, void* d_ws, size_t ws_size,
                              hipStream_t stream) {
  const float* x      = (const float*)d_in[0];
  const float* mask   = (const float*)d_in[1];
  const float* Wqkv   = (const float*)d_in[2];
  const float* bqkv   = (const float*)d_in[3];
  const float* Wout   = (const float*)d_in[4];
  const float* bout   = (const float*)d_in[5];
  const float* fsmn_w = (const float*)d_in[6];
  float* out = (float*)d_out;

  // workspace layout (bytes); vT aliases xb (xb dead after qkv GEMM). Total ~86 MB.
  char* ws = (char*)d_ws;
  u16* xb    = (u16*)ws;                         // 16,777,216  (also vT later)
  u16* vT    = (u16*)ws;
  u16* wqkvT = (u16*)(ws + 16777216);            //  1,572,864
  u16* woutT = (u16*)(ws + 18350080);            //    524,288
  u16* qkvb  = (u16*)(ws + 18874368);            // 50,331,648
  u16* ctxb  = (u16*)(ws + 69206016);            // 16,777,216

  cvt_f32_bf16<<<2048, 256, 0, stream>>>(x, xb, (NB*NT*ND)/4);
  transpose_cvt<<<dim3(1536/32, 512/32), dim3(32,8), 0, stream>>>(Wqkv, wqkvT, 512, 1536);
  transpose_cvt<<<dim3(512/32, 512/32),  dim3(32,8), 0, stream>>>(Wout, woutT, 512, 512);
  gemm_bt<0><<<dim3(1536/128, 16384/128), 256, 0, stream>>>(
      xb, wqkvT, bqkv, qkvb, nullptr, nullptr, NB*NT, QKV_LD, ND);
  vT_kernel<<<dim3(NDK/32, NT/32, NB*NH), dim3(32,8), 0, stream>>>(qkvb, vT);
  fsmn_kernel<<<dim3(NT/128, NB), 256, 0, stream>>>(qkvb, mask, fsmn_w, out);
  attn_kernel<<<dim3(NT/64, NB*NH), 256, 0, stream>>>(qkvb, vT, mask, ctxb);
  gemm_bt<1><<<dim3(512/128, 16384/128), 256, 0, stream>>>(
      ctxb, woutT, bout, nullptr, out, out, NB*NT, ND, ND);
}

// Round 2
// 265.416 us; speedup vs baseline: 1.2332x; 1.2332x over previous
//
#include <hip/hip_runtime.h>
#include <hip/hip_bf16.h>
#include <stdint.h>

// Problem constants (from reference)
#define NB 8
#define NT 2048
#define ND 512
#define NH 4
#define NDK 128
#define QKV_LD 1536   // row stride of qkv buffer (3*D)
#define KW 11

typedef unsigned short u16;
typedef __attribute__((ext_vector_type(4))) float f32x4;
typedef __attribute__((ext_vector_type(8))) short s16x8;   // 8 bf16 = 4 VGPR (guide §3)
typedef __attribute__((ext_vector_type(4))) unsigned short u16x4;
typedef __attribute__((ext_vector_type(4))) int i32x4;

#define AS1 __attribute__((address_space(1)))
#define AS3 __attribute__((address_space(3)))

__device__ __forceinline__ u16 f2bf(float f){
  unsigned u = __float_as_uint(f);
  u += 0x7fffu + ((u >> 16) & 1u);      // RNE
  return (u16)(u >> 16);
}
__device__ __forceinline__ float bf2f(u16 h){ return __uint_as_float(((unsigned)h) << 16); }
__device__ __forceinline__ unsigned pack2bf(float a, float b){
  float2 t; t.x = a; t.y = b;
  __hip_bfloat162 h = __float22bfloat162_rn(t);
  return *reinterpret_cast<unsigned*>(&h);
}

// ---------------------------------------------------------------- convert x -> bf16
__global__ void cvt_f32_bf16(const float* __restrict__ in, u16* __restrict__ out, int n4){
  int i = blockIdx.x * blockDim.x + threadIdx.x;
  const int stride = gridDim.x * blockDim.x;
  for (; i < n4; i += stride){
    float4 v = reinterpret_cast<const float4*>(in)[i];
    u16x4 o = { f2bf(v.x), f2bf(v.y), f2bf(v.z), f2bf(v.w) };
    reinterpret_cast<u16x4*>(out)[i] = o;
  }
}

// ------------------------------------------- transpose + convert f32 (RxC) -> bf16 (CxR)
__global__ void transpose_cvt(const float* __restrict__ in, u16* __restrict__ out, int R, int C){
  __shared__ float tile[32][33];
  const int cb = blockIdx.x * 32, rb = blockIdx.y * 32;
  const int tx = threadIdx.x, ty = threadIdx.y;   // (32,8)
  #pragma unroll
  for (int i = 0; i < 4; ++i)
    tile[ty + i*8][tx] = in[(size_t)(rb + ty + i*8) * C + cb + tx];
  __syncthreads();
  #pragma unroll
  for (int i = 0; i < 4; ++i)
    out[(size_t)(cb + ty + i*8) * R + rb + tx] = f2bf(tile[tx][ty + i*8]);
}

// ------------------------------------------- per-(b,h) transpose of V: (t,dk) -> (dk,t), bf16
__global__ void vT_kernel(const u16* __restrict__ qkvb, u16* __restrict__ vT){
  __shared__ u16 tile[32][33];
  const int z = blockIdx.z, b = z >> 2, h = z & 3;
  const u16* in = qkvb + (size_t)b * NT * QKV_LD + 2*ND + h * NDK;  // v block of qkv
  u16* outp = vT + (size_t)z * NDK * NT;
  const int db = blockIdx.x * 32, tb = blockIdx.y * 32;
  const int tx = threadIdx.x, ty = threadIdx.y;   // (32,8)
  #pragma unroll
  for (int i = 0; i < 4; ++i)
    tile[ty + i*8][tx] = in[(size_t)(tb + ty + i*8) * QKV_LD + db + tx];
  __syncthreads();
  #pragma unroll
  for (int i = 0; i < 4; ++i)
    outp[(size_t)(db + ty + i*8) * NT + tb + tx] = tile[tx][ty + i*8];
}

// ---------------------------------------------------------------- bf16 GEMM  C = A * Bt^T + bias
// A: MxK row-major bf16.  Bt: NxK row-major bf16 (i.e. B transposed).
// EPI==0: C -> bf16 buffer.  EPI==1: C -> f32 out, += resid (fsmn memory already in out buffer).
// 128x128 tile, BK=32, 4 waves, 4x4 16x16x32 MFMA per wave. 2-phase (m97 structure).
template<int EPI>
__global__ __launch_bounds__(256, 2) void gemm_bt(
    const u16* __restrict__ A, const u16* __restrict__ Bt, const float* __restrict__ bias,
    u16* __restrict__ Cb, float* __restrict__ Cf, const float* __restrict__ resid,
    int M, int N, int Kd)
{
  __shared__ u16 As[128 * 32];
  __shared__ u16 Bs[128 * 32];
  const int tid = threadIdx.x;
  const int m0 = blockIdx.y * 128, n0 = blockIdx.x * 128;
  const int w = tid >> 6, l = tid & 63, wr = w >> 1, wc = w & 1;
  const int r15 = l & 15, g = l >> 4;

  f32x4 acc[4][4] = {};

  const int row = tid >> 2, kc = tid & 3;       // chunk -> (row, 16B-chunk-in-row)
  const u16* Ag0 = A  + (size_t)(m0 + row)      * Kd + kc * 8;
  const u16* Ag1 = A  + (size_t)(m0 + row + 64) * Kd + kc * 8;
  const u16* Bg0 = Bt + (size_t)(n0 + row)      * Kd + kc * 8;
  const u16* Bg1 = Bt + (size_t)(n0 + row + 64) * Kd + kc * 8;
  u16* Al0 = &As[(size_t)tid * 8];
  u16* Al1 = &As[2048 + (size_t)tid * 8];
  u16* Bl0 = &Bs[(size_t)tid * 8];
  u16* Bl1 = &Bs[2048 + (size_t)tid * 8];

  for (int k0 = 0; k0 < Kd; k0 += 32){
    __builtin_amdgcn_global_load_lds((AS1 void*)(Ag0 + k0), (AS3 void*)Al0, 16, 0, 0);
    __builtin_amdgcn_global_load_lds((AS1 void*)(Ag1 + k0), (AS3 void*)Al1, 16, 0, 0);
    __builtin_amdgcn_global_load_lds((AS1 void*)(Bg0 + k0), (AS3 void*)Bl0, 16, 0, 0);
    __builtin_amdgcn_global_load_lds((AS1 void*)(Bg1 + k0), (AS3 void*)Bl1, 16, 0, 0);
    __syncthreads();
    s16x8 af[4], bfr[4];
    #pragma unroll
    for (int m = 0; m < 4; ++m)
      af[m] = *reinterpret_cast<const s16x8*>(&As[(wr*64 + m*16 + r15) * 32 + g*8]);
    #pragma unroll
    for (int n = 0; n < 4; ++n)
      bfr[n] = *reinterpret_cast<const s16x8*>(&Bs[(wc*64 + n*16 + r15) * 32 + g*8]);
    #pragma unroll
    for (int m = 0; m < 4; ++m){
      #pragma unroll
      for (int n = 0; n < 4; ++n)
        acc[m][n] = __builtin_amdgcn_mfma_f32_16x16x32_bf16(af[m], bfr[n], acc[m][n], 0, 0, 0);
    }
    __syncthreads();
  }

  // epilogue: C/D layout col = lane&15, row = (lane>>4)*4 + j  (guide §3, m89-verified)
  #pragma unroll
  for (int m = 0; m < 4; ++m){
    const int gr0 = m0 + wr*64 + m*16 + g*4;
    #pragma unroll
    for (int n = 0; n < 4; ++n){
      const int gc = n0 + wc*64 + n*16 + r15;
      const float bv = bias[gc];
      #pragma unroll
      for (int j = 0; j < 4; ++j){
        const size_t idx = (size_t)(gr0 + j) * N + gc;
        const float v = acc[m][n][j] + bv;
        if (EPI == 0) Cb[idx] = f2bf(v);
        else          Cf[idx] = v + resid[idx];
      }
    }
  }
}

// ---------------------------------------------------------------- FSMN depthwise conv (K=11, centered)
// out[b][t][d] = m[t] * ( vm[t][d] + sum_i w[d][i]*vm[t+i-5][d] ),  vm = m*v
__device__ __forceinline__ void load_vm(const u16* vb, const float* mb, int tau, float& a, float& c){
  if ((unsigned)tau >= (unsigned)NT){ a = 0.f; c = 0.f; return; }
  const float m = mb[tau];
  const unsigned pv = *reinterpret_cast<const unsigned*>(vb + (size_t)tau * QKV_LD);
  a = m * bf2f((u16)(pv & 0xffffu));
  c = m * bf2f((u16)(pv >> 16));
}

__global__ void fsmn_kernel(const u16* __restrict__ qkvb, const float* __restrict__ mask,
                            const float* __restrict__ fsmn_w, float* __restrict__ out)
{
  const int b = blockIdx.y;
  const int t0 = blockIdx.x * 128;
  const int d0 = threadIdx.x * 2;
  float w0[KW], w1[KW];
  #pragma unroll
  for (int i = 0; i < KW; ++i){ w0[i] = fsmn_w[d0*KW + i]; w1[i] = fsmn_w[(d0+1)*KW + i]; }
  const u16* vb = qkvb + (size_t)b * NT * QKV_LD + 2*ND + d0;
  const float* mb = mask + (size_t)b * NT;
  float v0[KW], v1[KW];                       // sliding vm window, tau = t-5+i
  #pragma unroll
  for (int i = 0; i < KW; ++i) load_vm(vb, mb, t0 - 5 + i, v0[i], v1[i]);
  for (int t = t0; t < t0 + 128; ++t){
    const float m = mb[t];
    float c0 = 0.f, c1 = 0.f;
    #pragma unroll
    for (int i = 0; i < KW; ++i){ c0 += w0[i]*v0[i]; c1 += w1[i]*v1[i]; }
    float2 o; o.x = m * (c0 + v0[5]); o.y = m * (c1 + v1[5]);
    *reinterpret_cast<float2*>(out + (size_t)(b*NT + t) * ND + d0) = o;
    #pragma unroll
    for (int i = 0; i < KW - 1; ++i){ v0[i] = v0[i+1]; v1[i] = v1[i+1]; }
    load_vm(vb, mb, t + 6, v0[KW-1], v1[KW-1]);
  }
}

// ---------------------------------------------------------------- flash attention
// 4 waves x 16 q-rows, 64-key tiles. SWAPPED QK^T: mfma(K,Q) -> lane owns ONE q-row
// (q = lane&15) with 16 k-values -> in-lane softmax + 2 shfl_xor. P stays in registers:
// pack bf16 pairs, redistribute 4(g)x4(n) u32 blocks into contiguous-k A-frags via shfl.
// K/V^T staged with XOR-swizzle via pre-swizzled global source (rule #21). T13 defer-max.
__global__ __launch_bounds__(256, 3) void attn_kernel(
    const u16* __restrict__ qkvb, const u16* __restrict__ vT,
    const float* __restrict__ mask, u16* __restrict__ ctxb)
{
  __shared__ u16 Ks[64 * 128];     // [key][dk], swizzled
  __shared__ u16 Vs[128 * 64];     // [dk][key], swizzled
  const int tid = threadIdx.x;
  const int w = tid >> 6, l = tid & 63, g = l >> 4, r15 = l & 15;
  const int q0 = blockIdx.x * 64;
  const int bh = blockIdx.y, b = bh >> 2, h = bh & 3;
  const u16* qb  = qkvb + (size_t)b * NT * QKV_LD + h * NDK;
  const u16* kb  = qb + ND;
  const u16* vtb = vT + (size_t)bh * NDK * NT;
  const float* mkp = mask + (size_t)b * NT;
  const float scale = 0.08838834764831845f;   // 1/sqrt(128)

  // Q fragments (B-operand now; same layout: lane r15 = q-row, 8 contiguous dk per g)
  s16x8 qf[4];
  {
    const u16* qrow = qb + (size_t)(q0 + w*16 + r15) * QKV_LD;
    #pragma unroll
    for (int ks = 0; ks < 4; ++ks)
      qf[ks] = *reinterpret_cast<const s16x8*>(qrow + ks*32 + g*8);
  }
  float mrun = -1e30f, lrun = 0.f;
  f32x4 oacc[8] = {};
  const int srcA = r15 + (g & 1) * 32;      // P-frag redistribution source lanes
  const int srcB = srcA + 16;
  const bool hiSel = (g >> 1) != 0;

  for (int kv0 = 0; kv0 < NT; kv0 += 64){
    #pragma unroll
    for (int i = 0; i < 4; ++i){          // K: 64 keys x 128 dk
      const int c = tid + i*256;
      const int kr = c >> 4, kc = c & 15;
      const u16* gp = kb + (size_t)(kv0 + kr) * QKV_LD + ((kc ^ (kr & 7)) << 3);
      __builtin_amdgcn_global_load_lds((AS1 void*)gp, (AS3 void*)&Ks[c*8], 16, 0, 0);
    }
    #pragma unroll
    for (int i = 0; i < 4; ++i){          // V^T: 128 dk x 64 keys
      const int c = tid + i*256;
      const int dr = c >> 3, kc = c & 7;
      const u16* gp = vtb + (size_t)dr * NT + kv0 + ((kc ^ (dr & 7)) << 3);
      __builtin_amdgcn_global_load_lds((AS1 void*)gp, (AS3 void*)&Vs[c*8], 16, 0, 0);
    }
    __syncthreads();

    // S^T = K Q^T : lane holds S[k = n*16+g*4+j][q = r15]
    f32x4 sc[4] = {};
    #pragma unroll
    for (int n = 0; n < 4; ++n){
      const int krow = n*16 + r15;
      #pragma unroll
      for (int ks = 0; ks < 4; ++ks){
        const int cb = (ks*64 + g*16) ^ ((krow & 7) << 4);
        s16x8 kf = *reinterpret_cast<const s16x8*>(&Ks[krow*128 + (cb >> 1)]);
        sc[n] = __builtin_amdgcn_mfma_f32_16x16x32_bf16(kf, qf[ks], sc[n], 0, 0, 0);
      }
    }
    // mask + scale; key index k = kv0 + n*16 + g*4 + j  (float4: j contiguous)
    #pragma unroll
    for (int n = 0; n < 4; ++n){
      const float4 mk4 = *reinterpret_cast<const float4*>(&mkp[kv0 + n*16 + g*4]);
      sc[n][0] = (mk4.x == 0.f) ? -3e30f : sc[n][0] * scale;
      sc[n][1] = (mk4.y == 0.f) ? -3e30f : sc[n][1] * scale;
      sc[n][2] = (mk4.z == 0.f) ? -3e30f : sc[n][2] * scale;
      sc[n][3] = (mk4.w == 0.f) ? -3e30f : sc[n][3] * scale;
    }
    // row max: 16 in-lane + 2 shfl_xor across g
    float tmx = sc[0][0];
    #pragma unroll
    for (int n = 0; n < 4; ++n){
      #pragma unroll
      for (int j = 0; j < 4; ++j) tmx = fmaxf(tmx, sc[n][j]);
    }
    tmx = fmaxf(tmx, __shfl_xor(tmx, 16));
    tmx = fmaxf(tmx, __shfl_xor(tmx, 32));

    // T13 defer-max: only rescale when some row's max grew by > 8
    if (!__all(tmx <= mrun + 8.f)){
      const float mn = fmaxf(mrun, tmx);
      const float corr = __expf(mrun - mn);
      mrun = mn;
      lrun *= corr;
      float cj[4];
      #pragma unroll
      for (int j = 0; j < 4; ++j) cj[j] = __shfl(corr, g*4 + j);  // PV-row mapping
      #pragma unroll
      for (int n8 = 0; n8 < 8; ++n8){
        #pragma unroll
        for (int j = 0; j < 4; ++j) oacc[n8][j] *= cj[j];
      }
    }
    // P = exp(S - mrun), row-sum
    float ts = 0.f;
    #pragma unroll
    for (int n = 0; n < 4; ++n){
      #pragma unroll
      for (int j = 0; j < 4; ++j){
        sc[n][j] = __expf(sc[n][j] - mrun);
        ts += sc[n][j];
      }
    }
    ts += __shfl_xor(ts, 16);
    ts += __shfl_xor(ts, 32);
    lrun += ts;
    // pack P to bf16 pairs: pk[n][p] covers k = n*16 + g*4 + {2p, 2p+1}
    unsigned pk[4][2];
    #pragma unroll
    for (int n = 0; n < 4; ++n){
      pk[n][0] = pack2bf(sc[n][0], sc[n][1]);
      pk[n][1] = pack2bf(sc[n][2], sc[n][3]);
    }
    // build PV A-frags: lane needs P[r15][kt*32 + g*8 .. +7]
    s16x8 pf[2];
    #pragma unroll
    for (int kt = 0; kt < 2; ++kt){
      const int a0 = __shfl((int)pk[kt*2][0],   srcA);
      const int a1 = __shfl((int)pk[kt*2][1],   srcA);
      const int a2 = __shfl((int)pk[kt*2][0],   srcB);
      const int a3 = __shfl((int)pk[kt*2][1],   srcB);
      const int b0 = __shfl((int)pk[kt*2+1][0], srcA);
      const int b1 = __shfl((int)pk[kt*2+1][1], srcA);
      const int b2 = __shfl((int)pk[kt*2+1][0], srcB);
      const int b3 = __shfl((int)pk[kt*2+1][1], srcB);
      union { i32x4 i; s16x8 h; } u;
      u.i[0] = hiSel ? b0 : a0;
      u.i[1] = hiSel ? b1 : a1;
      u.i[2] = hiSel ? b2 : a2;
      u.i[3] = hiSel ? b3 : a3;
      pf[kt] = u.h;
    }
    // O += P V  (unchanged orientation: oacc rows q = g*4+j, cols dk = n8*16+r15)
    #pragma unroll
    for (int kt = 0; kt < 2; ++kt){
      #pragma unroll
      for (int n8 = 0; n8 < 8; ++n8){
        const int vrow = n8*16 + r15;
        const int cb = (kt*64 + g*16) ^ ((vrow & 7) << 4);
        s16x8 vf = *reinterpret_cast<const s16x8*>(&Vs[vrow*64 + (cb >> 1)]);
        oacc[n8] = __builtin_amdgcn_mfma_f32_16x16x32_bf16(pf[kt], vf, oacc[n8], 0, 0, 0);
      }
    }
    __syncthreads();
  }
  // epilogue: lrun lives at lane (q, *); redistribute to PV-row mapping
  float rl[4];
  #pragma unroll
  for (int j = 0; j < 4; ++j){
    const float lr = __shfl(lrun, g*4 + j);
    rl[j] = (lr > 0.f) ? 1.f / lr : 0.f;
  }
  #pragma unroll
  for (int n8 = 0; n8 < 8; ++n8){
    #pragma unroll
    for (int j = 0; j < 4; ++j){
      const size_t r = (size_t)b*NT + q0 + w*16 + g*4 + j;
      ctxb[r*ND + h*NDK + n8*16 + r15] = f2bf(oacc[n8][j] * rl[j]);
    }
  }
}

// ---------------------------------------------------------------- launcher
extern "C" void kernel_launch(void* const* d_in, const int* in_sizes, int n_in,
                              void* d_out, int out_size, void* d_ws, size_t ws_size,
                              hipStream_t stream) {
  const float* x      = (const float*)d_in[0];
  const float* mask   = (const float*)d_in[1];
  const float* Wqkv   = (const float*)d_in[2];
  const float* bqkv   = (const float*)d_in[3];
  const float* Wout   = (const float*)d_in[4];
  const float* bout   = (const float*)d_in[5];
  const float* fsmn_w = (const float*)d_in[6];
  float* out = (float*)d_out;

  // workspace layout (bytes); vT aliases xb (xb dead after qkv GEMM). Total ~86 MB.
  char* ws = (char*)d_ws;
  u16* xb    = (u16*)ws;                         // 16,777,216  (also vT later)
  u16* vT    = (u16*)ws;
  u16* wqkvT = (u16*)(ws + 16777216);            //  1,572,864
  u16* woutT = (u16*)(ws + 18350080);            //    524,288
  u16* qkvb  = (u16*)(ws + 18874368);            // 50,331,648
  u16* ctxb  = (u16*)(ws + 69206016);            // 16,777,216

  cvt_f32_bf16<<<2048, 256, 0, stream>>>(x, xb, (NB*NT*ND)/4);
  transpose_cvt<<<dim3(1536/32, 512/32), dim3(32,8), 0, stream>>>(Wqkv, wqkvT, 512, 1536);
  transpose_cvt<<<dim3(512/32, 512/32),  dim3(32,8), 0, stream>>>(Wout, woutT, 512, 512);
  gemm_bt<0><<<dim3(1536/128, 16384/128), 256, 0, stream>>>(
      xb, wqkvT, bqkv, qkvb, nullptr, nullptr, NB*NT, QKV_LD, ND);
  vT_kernel<<<dim3(NDK/32, NT/32, NB*NH), dim3(32,8), 0, stream>>>(qkvb, vT);
  fsmn_kernel<<<dim3(NT/128, NB), 256, 0, stream>>>(qkvb, mask, fsmn_w, out);
  attn_kernel<<<dim3(NT/64, NB*NH), 256, 0, stream>>>(qkvb, vT, mask, ctxb);
  gemm_bt<1><<<dim3(512/128, 16384/128), 256, 0, stream>>>(
      ctxb, woutT, bout, nullptr, out, out, NB*NT, ND, ND);
}

// Round 3
// 238.593 us; speedup vs baseline: 1.3719x; 1.1124x over previous
//
#include <hip/hip_runtime.h>
#include <hip/hip_bf16.h>
#include <stdint.h>

// Problem constants (from reference)
#define NB 8
#define NT 2048
#define ND 512
#define NH 4
#define NDK 128
#define QKV_LD 1536   // row stride of qkv buffer (3*D)
#define KW 11

typedef unsigned short u16;
typedef __attribute__((ext_vector_type(4))) float f32x4;
typedef __attribute__((ext_vector_type(16))) float f32x16;
typedef __attribute__((ext_vector_type(4))) float fv4;
typedef __attribute__((ext_vector_type(8))) short s16x8;   // 8 bf16 = 4 VGPR
typedef __attribute__((ext_vector_type(4))) unsigned short u16x4;
typedef __attribute__((ext_vector_type(4))) int i32x4;

#define AS1 __attribute__((address_space(1)))
#define AS3 __attribute__((address_space(3)))

__device__ __forceinline__ u16 f2bf(float f){
  unsigned u = __float_as_uint(f);
  u += 0x7fffu + ((u >> 16) & 1u);      // RNE
  return (u16)(u >> 16);
}
__device__ __forceinline__ float bf2f(u16 h){ return __uint_as_float(((unsigned)h) << 16); }
__device__ __forceinline__ unsigned pack2bf(float a, float b){
  float2 t; t.x = a; t.y = b;
  __hip_bfloat162 h = __float22bfloat162_rn(t);
  return *reinterpret_cast<unsigned*>(&h);
}

// ---------------------------------------------------------------- convert x -> bf16
__global__ void cvt_f32_bf16(const float* __restrict__ in, u16* __restrict__ out, int n4){
  int i = blockIdx.x * blockDim.x + threadIdx.x;
  const int stride = gridDim.x * blockDim.x;
  for (; i < n4; i += stride){
    float4 v = reinterpret_cast<const float4*>(in)[i];
    u16x4 o = { f2bf(v.x), f2bf(v.y), f2bf(v.z), f2bf(v.w) };
    reinterpret_cast<u16x4*>(out)[i] = o;
  }
}

// ------------------------------------------- transpose + convert f32 (RxC) -> bf16 (CxR)
__global__ void transpose_cvt(const float* __restrict__ in, u16* __restrict__ out, int R, int C){
  __shared__ float tile[32][33];
  const int cb = blockIdx.x * 32, rb = blockIdx.y * 32;
  const int tx = threadIdx.x, ty = threadIdx.y;   // (32,8)
  #pragma unroll
  for (int i = 0; i < 4; ++i)
    tile[ty + i*8][tx] = in[(size_t)(rb + ty + i*8) * C + cb + tx];
  __syncthreads();
  #pragma unroll
  for (int i = 0; i < 4; ++i)
    out[(size_t)(cb + ty + i*8) * R + rb + tx] = f2bf(tile[tx][ty + i*8]);
}

// ------------------------------------------- per-(b,h) transpose of V: (t,dk) -> (dk,t), bf16
__global__ void vT_kernel(const u16* __restrict__ qkvb, u16* __restrict__ vT){
  __shared__ u16 tile[32][33];
  const int z = blockIdx.z, b = z >> 2, h = z & 3;
  const u16* in = qkvb + (size_t)b * NT * QKV_LD + 2*ND + h * NDK;  // v block of qkv
  u16* outp = vT + (size_t)z * NDK * NT;
  const int db = blockIdx.x * 32, tb = blockIdx.y * 32;
  const int tx = threadIdx.x, ty = threadIdx.y;   // (32,8)
  #pragma unroll
  for (int i = 0; i < 4; ++i)
    tile[ty + i*8][tx] = in[(size_t)(tb + ty + i*8) * QKV_LD + db + tx];
  __syncthreads();
  #pragma unroll
  for (int i = 0; i < 4; ++i)
    outp[(size_t)(db + ty + i*8) * NT + tb + tx] = tile[tx][ty + i*8];
}

// ---------------------------------------------------------------- bf16 GEMM  C = A * Bt^T + bias
template<int EPI>
__global__ __launch_bounds__(256, 2) void gemm_bt(
    const u16* __restrict__ A, const u16* __restrict__ Bt, const float* __restrict__ bias,
    u16* __restrict__ Cb, float* __restrict__ Cf, const float* __restrict__ resid,
    int M, int N, int Kd)
{
  __shared__ u16 As[128 * 32];
  __shared__ u16 Bs[128 * 32];
  const int tid = threadIdx.x;
  const int m0 = blockIdx.y * 128, n0 = blockIdx.x * 128;
  const int w = tid >> 6, l = tid & 63, wr = w >> 1, wc = w & 1;
  const int r15 = l & 15, g = l >> 4;

  f32x4 acc[4][4] = {};

  const int row = tid >> 2, kc = tid & 3;       // chunk -> (row, 16B-chunk-in-row)
  const u16* Ag0 = A  + (size_t)(m0 + row)      * Kd + kc * 8;
  const u16* Ag1 = A  + (size_t)(m0 + row + 64) * Kd + kc * 8;
  const u16* Bg0 = Bt + (size_t)(n0 + row)      * Kd + kc * 8;
  const u16* Bg1 = Bt + (size_t)(n0 + row + 64) * Kd + kc * 8;
  u16* Al0 = &As[(size_t)tid * 8];
  u16* Al1 = &As[2048 + (size_t)tid * 8];
  u16* Bl0 = &Bs[(size_t)tid * 8];
  u16* Bl1 = &Bs[2048 + (size_t)tid * 8];

  for (int k0 = 0; k0 < Kd; k0 += 32){
    __builtin_amdgcn_global_load_lds((AS1 void*)(Ag0 + k0), (AS3 void*)Al0, 16, 0, 0);
    __builtin_amdgcn_global_load_lds((AS1 void*)(Ag1 + k0), (AS3 void*)Al1, 16, 0, 0);
    __builtin_amdgcn_global_load_lds((AS1 void*)(Bg0 + k0), (AS3 void*)Bl0, 16, 0, 0);
    __builtin_amdgcn_global_load_lds((AS1 void*)(Bg1 + k0), (AS3 void*)Bl1, 16, 0, 0);
    __syncthreads();
    s16x8 af[4], bfr[4];
    #pragma unroll
    for (int m = 0; m < 4; ++m)
      af[m] = *reinterpret_cast<const s16x8*>(&As[(wr*64 + m*16 + r15) * 32 + g*8]);
    #pragma unroll
    for (int n = 0; n < 4; ++n)
      bfr[n] = *reinterpret_cast<const s16x8*>(&Bs[(wc*64 + n*16 + r15) * 32 + g*8]);
    #pragma unroll
    for (int m = 0; m < 4; ++m){
      #pragma unroll
      for (int n = 0; n < 4; ++n)
        acc[m][n] = __builtin_amdgcn_mfma_f32_16x16x32_bf16(af[m], bfr[n], acc[m][n], 0, 0, 0);
    }
    __syncthreads();
  }

  #pragma unroll
  for (int m = 0; m < 4; ++m){
    const int gr0 = m0 + wr*64 + m*16 + g*4;
    #pragma unroll
    for (int n = 0; n < 4; ++n){
      const int gc = n0 + wc*64 + n*16 + r15;
      const float bv = bias[gc];
      #pragma unroll
      for (int j = 0; j < 4; ++j){
        const size_t idx = (size_t)(gr0 + j) * N + gc;
        const float v = acc[m][n][j] + bv;
        if (EPI == 0) Cb[idx] = f2bf(v);
        else          Cf[idx] = v + resid[idx];
      }
    }
  }
}

// ---------------------------------------------------------------- FSMN depthwise conv (K=11, centered)
__device__ __forceinline__ void load_vm(const u16* vb, const float* mb, int tau, float& a, float& c){
  if ((unsigned)tau >= (unsigned)NT){ a = 0.f; c = 0.f; return; }
  const float m = mb[tau];
  const unsigned pv = *reinterpret_cast<const unsigned*>(vb + (size_t)tau * QKV_LD);
  a = m * bf2f((u16)(pv & 0xffffu));
  c = m * bf2f((u16)(pv >> 16));
}

__global__ void fsmn_kernel(const u16* __restrict__ qkvb, const float* __restrict__ mask,
                            const float* __restrict__ fsmn_w, float* __restrict__ out)
{
  const int b = blockIdx.y;
  const int t0 = blockIdx.x * 128;
  const int d0 = threadIdx.x * 2;
  float w0[KW], w1[KW];
  #pragma unroll
  for (int i = 0; i < KW; ++i){ w0[i] = fsmn_w[d0*KW + i]; w1[i] = fsmn_w[(d0+1)*KW + i]; }
  const u16* vb = qkvb + (size_t)b * NT * QKV_LD + 2*ND + d0;
  const float* mb = mask + (size_t)b * NT;
  float v0[KW], v1[KW];                       // sliding vm window, tau = t-5+i
  #pragma unroll
  for (int i = 0; i < KW; ++i) load_vm(vb, mb, t0 - 5 + i, v0[i], v1[i]);
  for (int t = t0; t < t0 + 128; ++t){
    const float m = mb[t];
    float c0 = 0.f, c1 = 0.f;
    #pragma unroll
    for (int i = 0; i < KW; ++i){ c0 += w0[i]*v0[i]; c1 += w1[i]*v1[i]; }
    float2 o; o.x = m * (c0 + v0[5]); o.y = m * (c1 + v1[5]);
    *reinterpret_cast<float2*>(out + (size_t)(b*NT + t) * ND + d0) = o;
    #pragma unroll
    for (int i = 0; i < KW - 1; ++i){ v0[i] = v0[i+1]; v1[i] = v1[i+1]; }
    load_vm(vb, mb, t + 6, v0[KW-1], v1[KW-1]);
  }
}

// ---------------------------------------------------------------- flash attention (8-wave, 32x32x16)
// Block: 512 thr = 8 waves, each wave owns 32 q-rows (QBLK=32), KV tiles of 64 keys.
// Swapped QK^T: mfma(A=K, B=Q) -> lane owns ONE q-row (q = lane&31), 32 scores in D regs.
// P->A-frag via 2x v_permlane32_swap_b32 per k-step (no LDS, no bpermute).
// Mask applied as p *= m post-exp (raw-score max is shift-consistent).
// K/V double-buffered in LDS (XOR-swizzled via pre-swizzled global source), 1 barrier/tile.
#define ATT_MFMA(a, bb, c) __builtin_amdgcn_mfma_f32_32x32x16_bf16(a, bb, c, 0, 0, 0)
#define C1F 0.12751741567f   /* (1/sqrt(128)) * log2(e) */

__global__ __launch_bounds__(512, 2) void attn_kernel(
    const u16* __restrict__ qkvb, const u16* __restrict__ vT,
    const float* __restrict__ mask, u16* __restrict__ ctxb)
{
  __shared__ u16 Ks[2][64 * 128];   // [key][dk], swizzled chunks
  __shared__ u16 Vs[2][128 * 64];   // [dk][key], swizzled chunks
  const int tid = threadIdx.x;
  const int w = tid >> 6, l = tid & 63, l31 = l & 31, hi = l >> 5;

  // XCD-bijective remap: 8 q-blocks of one bh land on one XCD (K/V L2 locality)
  const int lin = blockIdx.x + blockIdx.y * 8;    // grid = (8, 32)
  const int xcd = lin & 7, jj = lin >> 3;
  const int bh = xcd * 4 + (jj & 3), qblk = jj >> 2;
  const int b = bh >> 2, h = bh & 3;
  const int q0 = qblk * 256;

  const u16* qptr = qkvb + (size_t)b * NT * QKV_LD + h * NDK;
  const u16* kb   = qptr + ND;
  const u16* vtb  = vT + (size_t)bh * NDK * NT;
  const float* mkp = mask + (size_t)b * NT;

  // Q in registers (B-operand): lane holds Q[q0+w*32+l31][s*16 + hi*8 .. +7]
  s16x8 qf[8];
  {
    const u16* qrow = qptr + (size_t)(q0 + w*32 + l31) * QKV_LD;
    #pragma unroll
    for (int s = 0; s < 8; ++s)
      qf[s] = *reinterpret_cast<const s16x8*>(qrow + s*16 + hi*8);
  }

  float mrun = -1e30f, lrun = 0.f;
  f32x16 o0 = {}, o1 = {}, o2 = {}, o3 = {};

#define STAGE(buf, kvo) do { \
    _Pragma("unroll") \
    for (int i_ = 0; i_ < 2; ++i_){ \
      const int n_ = i_*512 + tid, kr_ = n_ >> 4, c_ = n_ & 15; \
      const u16* gp_ = kb + (size_t)((kvo) + kr_) * QKV_LD + ((c_ ^ (kr_ & 7)) << 3); \
      __builtin_amdgcn_global_load_lds((AS1 void*)gp_, (AS3 void*)&Ks[buf][n_*8], 16, 0, 0); \
    } \
    _Pragma("unroll") \
    for (int i_ = 0; i_ < 2; ++i_){ \
      const int n_ = i_*512 + tid, dr_ = n_ >> 3, kc_ = n_ & 7; \
      const u16* gp_ = vtb + (size_t)dr_ * NT + (kvo) + ((kc_ ^ (dr_ & 7)) << 3); \
      __builtin_amdgcn_global_load_lds((AS1 void*)gp_, (AS3 void*)&Vs[buf][n_*8], 16, 0, 0); \
    } \
  } while(0)

  STAGE(0, 0);
  __syncthreads();
  int cur = 0;

  for (int t = 0; t < NT/64; ++t){
    const int kv0 = t * 64;
    if (t + 1 < NT/64) STAGE(cur ^ 1, kv0 + 64);

    // mask for this tile: lane's k-locals are b32*32 + r8*8 + 4*hi + j
    fv4 mA[4], mB[4];
    #pragma unroll
    for (int r8 = 0; r8 < 4; ++r8){
      mA[r8] = *reinterpret_cast<const fv4*>(&mkp[kv0      + r8*8 + hi*4]);
      mB[r8] = *reinterpret_cast<const fv4*>(&mkp[kv0 + 32 + r8*8 + hi*4]);
    }

    // S^T = K Q^T: d0 covers keys kv0+0..31, d1 keys kv0+32..63; lane owns q-col l31
    f32x16 d0 = {}, d1 = {};
    #pragma unroll
    for (int s = 0; s < 8; ++s){
      const int cg = s*2 + hi;
      s16x8 kf0 = *reinterpret_cast<const s16x8*>(
          &Ks[cur][ l31*128        + ((cg ^ (l31 & 7)) << 3) ]);
      s16x8 kf1 = *reinterpret_cast<const s16x8*>(
          &Ks[cur][ (32+l31)*128   + ((cg ^ (l31 & 7)) << 3) ]);
      d0 = ATT_MFMA(kf0, qf[s], d0);
      d1 = ATT_MFMA(kf1, qf[s], d1);
    }

    // row max over raw scores (32 in-lane + 1 cross-half)
    float tmx = d0[0];
    #pragma unroll
    for (int r = 1; r < 16; ++r) tmx = fmaxf(tmx, d0[r]);
    #pragma unroll
    for (int r = 0; r < 16; ++r) tmx = fmaxf(tmx, d1[r]);
    tmx = fmaxf(tmx, __shfl_xor(tmx, 32));

    // T13 defer-max (raw-score threshold 64 ~ 8 nats)
    if (!__all(tmx <= mrun + 64.f)){
      const float mn = fmaxf(mrun, tmx);
      const float corr = exp2f((mrun - mn) * C1F);
      mrun = mn; lrun *= corr;
      #pragma unroll
      for (int r = 0; r < 16; ++r){
        const int qs = (r & 3) + 8*(r >> 2) + 4*hi;
        const float cq = __shfl(corr, qs);
        o0[r] *= cq; o1[r] *= cq; o2[r] *= cq; o3[r] *= cq;
      }
    }

    // p = exp2(fma(s, c1, -m*c1)) * mask; in-place into d0/d1; accumulate l
    const float mm = mrun * C1F;
    float ts = 0.f;
    #pragma unroll
    for (int r = 0; r < 16; ++r){
      const int r8 = r >> 2, j = r & 3;
      const float p0 = exp2f(fmaf(d0[r], C1F, -mm)) * mA[r8][j];
      const float p1 = exp2f(fmaf(d1[r], C1F, -mm)) * mB[r8][j];
      d0[r] = p0; d1[r] = p1; ts += p0 + p1;
    }
    ts += __shfl_xor(ts, 32);
    lrun += ts;

    // pack p -> bf16 pairs
    unsigned pku[2][4][2];
    #pragma unroll
    for (int r8 = 0; r8 < 4; ++r8){
      pku[0][r8][0] = pack2bf(d0[4*r8+0], d0[4*r8+1]);
      pku[0][r8][1] = pack2bf(d0[4*r8+2], d0[4*r8+3]);
      pku[1][r8][0] = pack2bf(d1[4*r8+0], d1[4*r8+1]);
      pku[1][r8][1] = pack2bf(d1[4*r8+2], d1[4*r8+3]);
    }

    // PV: per k-step build A-frag with 2 permlane32_swap, then 4 dk-blocks
    #pragma unroll
    for (int ks = 0; ks < 4; ++ks){
      const int bb = ks >> 1, rlo = (ks & 1) * 2;
      int u0 = (int)pku[bb][rlo][0],   u1 = (int)pku[bb][rlo][1];
      int v0 = (int)pku[bb][rlo+1][0], v1 = (int)pku[bb][rlo+1][1];
      asm("v_permlane32_swap_b32 %0, %1" : "+v"(u0), "+v"(v0));
      asm("v_permlane32_swap_b32 %0, %1" : "+v"(u1), "+v"(v1));
      union { i32x4 i; s16x8 hv; } pu;
      pu.i[0] = u0; pu.i[1] = u1; pu.i[2] = v0; pu.i[3] = v1;
      const int cg = ks*2 + hi;
      {
        const int dr = l31;
        s16x8 vf = *reinterpret_cast<const s16x8*>(&Vs[cur][ dr*64 + ((cg ^ (dr&7)) << 3) ]);
        o0 = ATT_MFMA(pu.hv, vf, o0);
      }
      {
        const int dr = 32 + l31;
        s16x8 vf = *reinterpret_cast<const s16x8*>(&Vs[cur][ dr*64 + ((cg ^ (dr&7)) << 3) ]);
        o1 = ATT_MFMA(pu.hv, vf, o1);
      }
      {
        const int dr = 64 + l31;
        s16x8 vf = *reinterpret_cast<const s16x8*>(&Vs[cur][ dr*64 + ((cg ^ (dr&7)) << 3) ]);
        o2 = ATT_MFMA(pu.hv, vf, o2);
      }
      {
        const int dr = 96 + l31;
        s16x8 vf = *reinterpret_cast<const s16x8*>(&Vs[cur][ dr*64 + ((cg ^ (dr&7)) << 3) ]);
        o3 = ATT_MFMA(pu.hv, vf, o3);
      }
    }

    __syncthreads();
    cur ^= 1;
  }

  // epilogue: O[q][dk] regs: col dk = dkblk*32 + l31, row q = (r&3)+8*(r>>2)+4*hi
  #pragma unroll
  for (int r = 0; r < 16; ++r){
    const int qs = (r & 3) + 8*(r >> 2) + 4*hi;
    const float lr = __shfl(lrun, qs);
    const float rl = (lr > 0.f) ? (1.f / lr) : 0.f;
    const int row = q0 + w*32 + qs;
    u16* cp = ctxb + (size_t)(b*NT + row) * ND + h*NDK + l31;
    cp[0]  = f2bf(o0[r] * rl);
    cp[32] = f2bf(o1[r] * rl);
    cp[64] = f2bf(o2[r] * rl);
    cp[96] = f2bf(o3[r] * rl);
  }
#undef STAGE
}

// ---------------------------------------------------------------- launcher
extern "C" void kernel_launch(void* const* d_in, const int* in_sizes, int n_in,
                              void* d_out, int out_size, void* d_ws, size_t ws_size,
                              hipStream_t stream) {
  const float* x      = (const float*)d_in[0];
  const float* mask   = (const float*)d_in[1];
  const float* Wqkv   = (const float*)d_in[2];
  const float* bqkv   = (const float*)d_in[3];
  const float* Wout   = (const float*)d_in[4];
  const float* bout   = (const float*)d_in[5];
  const float* fsmn_w = (const float*)d_in[6];
  float* out = (float*)d_out;

  // workspace layout (bytes); vT aliases xb (xb dead after qkv GEMM). Total ~86 MB.
  char* ws = (char*)d_ws;
  u16* xb    = (u16*)ws;                         // 16,777,216  (also vT later)
  u16* vT    = (u16*)ws;
  u16* wqkvT = (u16*)(ws + 16777216);            //  1,572,864
  u16* woutT = (u16*)(ws + 18350080);            //    524,288
  u16* qkvb  = (u16*)(ws + 18874368);            // 50,331,648
  u16* ctxb  = (u16*)(ws + 69206016);            // 16,777,216

  cvt_f32_bf16<<<2048, 256, 0, stream>>>(x, xb, (NB*NT*ND)/4);
  transpose_cvt<<<dim3(1536/32, 512/32), dim3(32,8), 0, stream>>>(Wqkv, wqkvT, 512, 1536);
  transpose_cvt<<<dim3(512/32, 512/32),  dim3(32,8), 0, stream>>>(Wout, woutT, 512, 512);
  gemm_bt<0><<<dim3(1536/128, 16384/128), 256, 0, stream>>>(
      xb, wqkvT, bqkv, qkvb, nullptr, nullptr, NB*NT, QKV_LD, ND);
  vT_kernel<<<dim3(NDK/32, NT/32, NB*NH), dim3(32,8), 0, stream>>>(qkvb, vT);
  fsmn_kernel<<<dim3(NT/128, NB), 256, 0, stream>>>(qkvb, mask, fsmn_w, out);
  attn_kernel<<<dim3(8, 32), 512, 0, stream>>>(qkvb, vT, mask, ctxb);
  gemm_bt<1><<<dim3(512/128, 16384/128), 256, 0, stream>>>(
      ctxb, woutT, bout, nullptr, out, out, NB*NT, ND, ND);
}